// Round 14
// baseline (243.020 us; speedup 1.0000x reference)
//
#include <hip/hip_runtime.h>
#include <math.h>

// Problem constants (B, L, D, DH from the reference)
#define WS_B  4
#define WS_L  2048
#define WS_D  1024
#define WS_DH 2048
#define WS_M  (WS_B * WS_L)        // 8192 rows (B*L)
#define NCH   128                   // scan chunks per sequence
#define CHUNK (WS_L / NCH)          // 16 timesteps per chunk
#define CB    8                     // channels per scan thread (f16x8 loads)

typedef __attribute__((ext_vector_type(4))) float     f32x4;
typedef _Float16 f16x8 __attribute__((ext_vector_type(8)));   // MFMA A/B frag (4 VGPRs)

#define GLDS(gptr, lptr) \
    __builtin_amdgcn_global_load_lds( \
        (const __attribute__((address_space(1))) unsigned int*)(gptr), \
        (__attribute__((address_space(3))) unsigned int*)(lptr), 16, 0, 0)

// R17: cooperative fusion REVERTED (R16 failed: grid.sync() gave no real
// inter-phase dependency under graph capture — absmax 6.38 = stale-data
// signature). Back to the verified R15 3-kernel scan. Added this round:
// (a) MLP-hoist of the 16 h-loads in scan_local/scan_apply (grid-limited
//     occupancy -> per-thread ILP is the only latency lever; bit-identical),
// (b) T1 bijective XCD swizzle on both GEMMs (index remap only).

// ---- convert: elementwise f32 -> f16 for x, W_in, W_out (one kernel) ----
__global__ __launch_bounds__(256)
void convert_f16(const float* __restrict__ x,  _Float16* __restrict__ xh,
                 const float* __restrict__ w1, _Float16* __restrict__ w1h,
                 const float* __restrict__ w2, _Float16* __restrict__ w2h) {
    const int n1 = WS_M * WS_D / 8;          // x chunks
    const int n2 = WS_DH * WS_D / 8;         // W_in chunks
    const int n3 = WS_D * WS_DH / 8;         // W_out chunks
    int t = blockIdx.x * 256 + threadIdx.x;
    const float* s; _Float16* d; int off;
    if (t < n1)            { s = x;  d = xh;  off = t; }
    else if (t < n1 + n2)  { s = w1; d = w1h; off = t - n1; }
    else if (t < n1 + n2 + n3) { s = w2; d = w2h; off = t - n1 - n2; }
    else return;
    f32x4 v0 = *(const f32x4*)(s + (size_t)off * 8);
    f32x4 v1 = *(const f32x4*)(s + (size_t)off * 8 + 4);
    f16x8 h;
#pragma unroll
    for (int k = 0; k < 4; ++k) { h[k] = (_Float16)v0[k]; h[4 + k] = (_Float16)v1[k]; }
    *(f16x8*)(d + (size_t)off * 8) = h;
}

// ---- GEMM:  C[m,n] = sum_k A[m,k]*B[n,k] + bias[n] ----
// A [M][K], B [N][K] row-major f16. 128x128 tile, BK=64, dbuf, counted-vmcnt
// ring (2-deep prefetch, vmcnt(8) in-loop, vmcnt(0) only peeled). LDS tile
// [128][64] XOR-swizzled: granule (row,kq) at slot row*8 + (kq^(row&7));
// linear GLDS dest + inverse-swizzled source + swizzled ds_read (rule #21).
// R17: T1 XCD swizzle — flat ids with flat%8==k land on XCD k (round-robin
// dispatch); remap swz=(flat&7)*(nwg/8)+(flat>>3) so each XCD owns a
// contiguous bn range -> B panels L2-resident. Bijective (nwg%8==0).
template<int K, int LDC, int GY, int MINB, typename OutT>
__global__ __launch_bounds__(256, MINB)
void gemm_f16(const _Float16* __restrict__ A, const _Float16* __restrict__ B,
              const float* __restrict__ bias, OutT* __restrict__ C)
{
    __shared__ alignas(16) _Float16 sA[2][128 * 64];
    __shared__ alignas(16) _Float16 sB[2][128 * 64];

    const int tid  = threadIdx.x;
    const int lane = tid & 63;
    const int wave = tid >> 6;
    const int wm   = (wave >> 1) * 64;
    const int wn   = (wave & 1) * 64;
    const int m15  = lane & 15;
    const int q    = lane >> 4;

    // T1 XCD-aware remap of the flat block id (grid is 64 x GY, x-major)
    constexpr int NWG = 64 * GY;
    int flat = blockIdx.y * 64 + blockIdx.x;
    int swz  = (flat & 7) * (NWG >> 3) + (flat >> 3);
    const int bm = swz & 63;
    const int bn = swz >> 6;

    f32x4 acc[4][4] = {};

    auto stage = [&](int kc0, int buf) {
#pragma unroll
        for (int i = 0; i < 4; ++i) {
            int c   = i * 256 + tid;
            int row = c >> 3;
            int kqs = (c & 7) ^ (row & 7);   // inverse swizzle on SOURCE
            GLDS(A + (size_t)(bm * 128 + row) * K + kc0 + kqs * 8, &sA[buf][c * 8]);
            GLDS(B + (size_t)(bn * 128 + row) * K + kc0 + kqs * 8, &sB[buf][c * 8]);
        }
    };

    auto compute = [&](int bufc) {
#pragma unroll
        for (int kk = 0; kk < 2; ++kk) {
            f16x8 af[4], bf[4];
            int kq = kk * 4 + q;
#pragma unroll
            for (int i = 0; i < 4; ++i) {
                int ra = wm + i * 16 + m15;
                int rb = wn + i * 16 + m15;
                af[i] = *(const f16x8*)&sA[bufc][ra * 64 + ((kq ^ (ra & 7)) << 3)];
                bf[i] = *(const f16x8*)&sB[bufc][rb * 64 + ((kq ^ (rb & 7)) << 3)];
            }
#pragma unroll
            for (int i = 0; i < 4; ++i)
#pragma unroll
                for (int j = 0; j < 4; ++j)
                    acc[i][j] = __builtin_amdgcn_mfma_f32_16x16x32_f16(af[i], bf[j], acc[i][j], 0, 0, 0);
        }
    };

    stage(0, 0);
    stage(64, 1);

    int buf = 0;
    int kc0 = 0;
    for (; kc0 + 64 < K; kc0 += 64, buf ^= 1) {
        asm volatile("s_waitcnt vmcnt(8)" ::: "memory");   // this buf's 8 landed
        __builtin_amdgcn_sched_barrier(0);
        __builtin_amdgcn_s_barrier();

        compute(buf);

        __builtin_amdgcn_sched_barrier(0);
        __builtin_amdgcn_s_barrier();                       // all waves done with buf
        if (kc0 + 128 < K) stage(kc0 + 128, buf);
    }

    asm volatile("s_waitcnt vmcnt(0)" ::: "memory");        // peeled last kstep
    __builtin_amdgcn_sched_barrier(0);
    __builtin_amdgcn_s_barrier();
    compute(buf);

    const int r4 = (lane >> 4) * 4;   // C/D: col=lane&15, row=(lane>>4)*4+reg (m89)
#pragma unroll
    for (int j = 0; j < 4; ++j) {
        int col = bn * 128 + wn + j * 16 + m15;
        float bv = bias[col];
#pragma unroll
        for (int i = 0; i < 4; ++i) {
            int row0 = bm * 128 + wm + i * 16 + r4;
#pragma unroll
            for (int r = 0; r < 4; ++r)
                C[(size_t)(row0 + r) * LDC + col] = (OutT)(acc[i][j][r] + bv);
        }
    }
}

// ---- scan: U[t] = p*U[t-1] + p0*h[t], U[-1]=last;  z[t]=Re(U[t]); y=silu(z) ----
__device__ inline void compute_p(const float* __restrict__ phazor, int c, float& pre, float& pim) {
    float zr = phazor[2 * c], zi = phazor[2 * c + 1];
    float pa = sqrtf(zr * zr + zi * zi);
    float sc = expf(-pa) / pa;       // unit phase * exp(-|p|) magnitude
    pre = zr * sc;
    pim = zi * sc;
}

// phase 1: per-chunk local scan (init 0), write chunk-end states (8 channels)
// R17: all 16 h-loads hoisted ahead of the recurrence (MLP=16; grid-limited
// occupancy means ILP is the only latency hiding). Compile-time indices only.
__global__ void scan_local(const _Float16* __restrict__ h, const float* __restrict__ phazor,
                           const float* __restrict__ phazor_init, float* __restrict__ Uend) {
    int idx = blockIdx.x * blockDim.x + threadIdx.x;      // [0, B*NCH*DH/CB)
    int cb   = idx & (WS_DH / CB - 1);                     // 256 channel-blocks
    int rest = idx >> 8;
    int j    = rest & (NCH - 1);
    int b    = rest >> 7;
    int c0   = cb * CB;
    const int row0 = b * WS_L + j * CHUNK;
    const _Float16* hp = h + (size_t)row0 * WS_DH + c0;
    f16x8 v[CHUNK];
#pragma unroll
    for (int t = 0; t < CHUNK; ++t) v[t] = *(const f16x8*)(hp + (size_t)t * WS_DH);

    float pre[CB], pim[CB], p0r[CB], p0i[CB], ur[CB] = {}, ui[CB] = {};
#pragma unroll
    for (int u = 0; u < CB; ++u) {
        compute_p(phazor, c0 + u, pre[u], pim[u]);
        p0r[u] = phazor_init[2 * (c0 + u)];
        p0i[u] = phazor_init[2 * (c0 + u) + 1];
    }
#pragma unroll
    for (int t = 0; t < CHUNK; ++t) {
#pragma unroll
        for (int u = 0; u < CB; ++u) {
            float hv = (float)v[t][u];
            float nr = fmaf(pre[u], ur[u], fmaf(-pim[u], ui[u], p0r[u] * hv));
            float ni = fmaf(pre[u], ui[u], fmaf( pim[u], ur[u], p0i[u] * hv));
            ur[u] = nr; ui[u] = ni;
        }
    }
    float2* Ue = (float2*)Uend;
    size_t o = ((size_t)(b * NCH + j)) * WS_DH + c0;
#pragma unroll
    for (int u = 0; u < CB; ++u) { float2 w; w.x = ur[u]; w.y = ui[u]; Ue[o + u] = w; }
}

// phase 2: wave-parallel chunk combine (Kogge-Stone over 64 super-chunks of
// coefficient q^2, q = p^CHUNK constant per channel).
__global__ __launch_bounds__(256)
void scan_carry(const float* __restrict__ Uend, float* __restrict__ carry,
                const float* __restrict__ phazor,
                const float* __restrict__ last_re, const float* __restrict__ last_im) {
    __shared__ float2 T[16][NCH + 1];
    const int tid = threadIdx.x;
    const int blk = blockIdx.x;           // [0, B*DH/16) = 512
    const int b   = blk >> 7;             // 128 blocks per batch
    const int c0  = (blk & 127) * 16;

    const float2* Ue = (const float2*)Uend;
    float2* Ca = (float2*)carry;

    // phase A: load Uend[b][k][c0..c0+15] -> T[c_l][k]  (128B segments)
    {
        int c_l = tid & 15, kq = tid >> 4;
#pragma unroll
        for (int pass = 0; pass < NCH / 16; ++pass) {
            int k = pass * 16 + kq;
            T[c_l][k] = Ue[(size_t)(b * NCH + k) * WS_DH + c0 + c_l];
        }
    }
    __syncthreads();

    // phase B: 4 waves x 4 passes = 16 channels; lane j owns chunks 2j, 2j+1
    const int j  = tid & 63;
    const int wv = tid >> 6;
#pragma unroll
    for (int pass = 0; pass < 4; ++pass) {
        int c_l = pass * 4 + wv;
        int c   = c0 + c_l;
        float pre, pim;
        compute_p(phazor, c, pre, pim);
        float qr = pre, qi = pim;          // q = p^CHUNK via 4 squarings (CHUNK=16)
#pragma unroll
        for (int s = 0; s < 4; ++s) { float nr = qr*qr - qi*qi; qi = 2.f*qr*qi; qr = nr; }
        float q2r = qr*qr - qi*qi, q2i = 2.f*qr*qi;   // q^2 = p^32

        float2 L0 = T[c_l][2*j], L1 = T[c_l][2*j + 1];
        // super-chunk local sum: Ls = L1 + q*L0
        float lsr = fmaf(qr, L0.x, fmaf(-qi, L0.y, L1.x));
        float lsi = fmaf(qr, L0.y, fmaf( qi, L0.x, L1.y));
        // w = (q^2)^j via binary expansion of j
        float wr = 1.f, wi = 0.f, sr = q2r, si = q2i;
#pragma unroll
        for (int s = 0; s < 6; ++s) {
            if ((j >> s) & 1) { float nr = wr*sr - wi*si; wi = wr*si + wi*sr; wr = nr; }
            float n2 = sr*sr - si*si; si = 2.f*sr*si; sr = n2;
        }
        // Kogge-Stone inclusive scan: x[j] = sum_i (q^2)^(j-i) * Ls[i]
        float xr = lsr, xi = lsi, ar = q2r, ai = q2i;
#pragma unroll
        for (int o = 1; o < 64; o <<= 1) {
            float rr = __shfl_up(xr, o);
            float ri = __shfl_up(xi, o);
            if (j >= o) {
                xr = fmaf(ar, rr, fmaf(-ai, ri, xr));
                xi = fmaf(ar, ri, fmaf( ai, rr, xi));
            }
            float n2 = ar*ar - ai*ai; ai = 2.f*ar*ai; ar = n2;
        }
        // carry entering super-chunk j: C = w*last + x[j-1]
        float tpr = __shfl_up(xr, 1), tpi = __shfl_up(xi, 1);
        if (j == 0) { tpr = 0.f; tpi = 0.f; }
        float Lre = last_re[b * WS_DH + c], Lim = last_im[b * WS_DH + c];
        float cer = fmaf(wr, Lre, fmaf(-wi, Lim, tpr));
        float cei = fmaf(wr, Lim, fmaf( wi, Lre, tpi));
        // carry[2j] = C ; carry[2j+1] = q*C + L0   (disjoint slots per lane)
        float cor = fmaf(qr, cer, fmaf(-qi, cei, L0.x));
        float coi = fmaf(qr, cei, fmaf( qi, cer, L0.y));
        T[c_l][2*j]     = make_float2(cer, cei);
        T[c_l][2*j + 1] = make_float2(cor, coi);
    }
    __syncthreads();

    // phase C: write carry[b][k][c0..c0+15] back (128B segments)
    {
        int c_l = tid & 15, kq = tid >> 4;
#pragma unroll
        for (int pass = 0; pass < NCH / 16; ++pass) {
            int k = pass * 16 + kq;
            Ca[(size_t)(b * NCH + k) * WS_DH + c0 + c_l] = T[c_l][k];
        }
    }
}

// phase 3: re-scan from carry, silu, write y ROW-MAJOR f16 (hoisted loads).
__global__ void scan_apply(const _Float16* __restrict__ h, const float* __restrict__ phazor,
                           const float* __restrict__ phazor_init, const float* __restrict__ carry,
                           _Float16* __restrict__ yh) {
    int idx = blockIdx.x * blockDim.x + threadIdx.x;
    int cb   = idx & (WS_DH / CB - 1);
    int rest = idx >> 8;
    int j    = rest & (NCH - 1);
    int b    = rest >> 7;
    int c0   = cb * CB;
    const int row0 = b * WS_L + j * CHUNK;
    const _Float16* hp = h + (size_t)row0 * WS_DH + c0;
    f16x8 v[CHUNK];
#pragma unroll
    for (int t = 0; t < CHUNK; ++t) v[t] = *(const f16x8*)(hp + (size_t)t * WS_DH);

    float pre[CB], pim[CB], p0r[CB], p0i[CB], ur[CB], ui[CB];
    const float2* Ca = (const float2*)carry;
    size_t co = ((size_t)(b * NCH + j)) * WS_DH + c0;
#pragma unroll
    for (int u = 0; u < CB; ++u) {
        compute_p(phazor, c0 + u, pre[u], pim[u]);
        p0r[u] = phazor_init[2 * (c0 + u)];
        p0i[u] = phazor_init[2 * (c0 + u) + 1];
        float2 w = Ca[co + u];
        ur[u] = w.x; ui[u] = w.y;
    }
    _Float16* yp = yh + (size_t)row0 * WS_DH + c0;
#pragma unroll
    for (int t = 0; t < CHUNK; ++t) {
        f16x8 yv;
#pragma unroll
        for (int u = 0; u < CB; ++u) {
            float hv = (float)v[t][u];
            float nr = fmaf(pre[u], ur[u], fmaf(-pim[u], ui[u], p0r[u] * hv));
            float ni = fmaf(pre[u], ui[u], fmaf( pim[u], ur[u], p0i[u] * hv));
            ur[u] = nr; ui[u] = ni;
            float z = nr;                                   // Re(U[t])
            yv[u] = (_Float16)(z / (1.f + expf(-z)));       // silu
        }
        *(f16x8*)(yp + (size_t)t * WS_DH) = yv;
    }
}

extern "C" void kernel_launch(void* const* d_in, const int* in_sizes, int n_in,
                              void* d_out, int out_size, void* d_ws, size_t ws_size,
                              hipStream_t stream)
{
    const float* x       = (const float*)d_in[0];
    const float* W_in    = (const float*)d_in[1];
    const float* b_in    = (const float*)d_in[2];
    const float* W_out   = (const float*)d_in[3];
    const float* b_out   = (const float*)d_in[4];
    const float* phazor  = (const float*)d_in[5];
    const float* ph_init = (const float*)d_in[6];
    const float* last_re = (const float*)d_in[7];
    const float* last_im = (const float*)d_in[8];
    float* out = (float*)d_out;

    // workspace carve-up (76 MB via aliasing).
    char* ws = (char*)d_ws;
    size_t off = 0;
    auto alloc = [&](size_t bytes) {
        char* p = ws + off;
        off += (bytes + 255) & ~(size_t)255;
        return p;
    };
    _Float16* h     = (_Float16*)alloc((size_t)WS_M * WS_DH * 2);    // 32 MB
    _Float16* w2h   = (_Float16*)alloc((size_t)WS_D * WS_DH * 2);    //  4 MB
    char*     alias0 = ws + off;
    _Float16* xh    = (_Float16*)alloc((size_t)WS_M * WS_D * 2);     // 16 MB
    _Float16* w1h   = (_Float16*)alloc((size_t)WS_DH * WS_D * 2);    //  4 MB
    float*    Uend  = (float*)alloc((size_t)WS_B * NCH * WS_DH * 2 * 4); // 8 MB
    alloc((size_t)4 * 1024 * 1024);                                  //  4 MB pad
    float*    carry = (float*)alloc((size_t)WS_B * NCH * WS_DH * 2 * 4); // 8 MB
    _Float16* yh    = (_Float16*)alias0;                             // 32 MB aliased

    // 1) convert all three inputs to f16 row-major (pure elementwise)
    {
        int n = (WS_M * WS_D + WS_DH * WS_D + WS_D * WS_DH) / 8;
        convert_f16<<<dim3((n + 255) / 256), dim3(256), 0, stream>>>(x, xh, W_in, w1h, W_out, w2h);
    }

    // 2) h = x @ W_in^T + b_in   [8192, 2048] f16, grid 64x16 = 1024 blocks
    {
        dim3 g(WS_M / 128, WS_DH / 128);
        gemm_f16<WS_D, WS_DH, 16, 2, _Float16><<<g, dim3(256), 0, stream>>>(xh, w1h, b_in, h);
    }

    // 3) chunked complex scan + silu -> yh (f16 row-major), 3 kernels
    {
        int total = WS_B * NCH * WS_DH / CB;               // 131072 threads
        scan_local<<<dim3(total / 256), dim3(256), 0, stream>>>(h, phazor, ph_init, Uend);
        scan_carry<<<dim3(WS_B * WS_DH / 16), dim3(256), 0, stream>>>(Uend, carry, phazor,
                                                                      last_re, last_im);
        scan_apply<<<dim3(total / 256), dim3(256), 0, stream>>>(h, phazor, ph_init, carry, yh);
    }

    // 4) out = yh @ W_out^T + b_out, K=2048, grid 64x8 = 512 blocks
    {
        dim3 g(WS_M / 128, WS_D / 128);
        gemm_f16<WS_DH, WS_D, 8, 2, float><<<g, dim3(256), 0, stream>>>(yh, w2h, b_out, out);
    }
}

// Round 18
// 214.568 us; speedup vs baseline: 1.1326x; 1.1326x over previous
//
#include <hip/hip_runtime.h>
#include <math.h>

// Problem constants (B, L, D, DH from the reference)
#define WS_B  4
#define WS_L  2048
#define WS_D  1024
#define WS_DH 2048
#define WS_M  (WS_B * WS_L)        // 8192 rows (B*L)
#define NCH   128                   // scan chunks per sequence
#define CHUNK (WS_L / NCH)          // 16 timesteps per chunk
#define CB    4                     // channels per scan thread (R18: 8->4, 2x TLP)
#define CBL   (WS_DH / CB)          // 512 channel-blocks

typedef __attribute__((ext_vector_type(4))) float     f32x4;
typedef _Float16 f16x8 __attribute__((ext_vector_type(8)));   // MFMA A/B frag (4 VGPRs)
typedef _Float16 f16x4 __attribute__((ext_vector_type(4)));

#define GLDS(gptr, lptr) \
    __builtin_amdgcn_global_load_lds( \
        (const __attribute__((address_space(1))) unsigned int*)(gptr), \
        (__attribute__((address_space(3))) unsigned int*)(lptr), 16, 0, 0)

// R18: XCD swizzle REVERTED — R17 counters: GEMM1 FETCH 32.8->133 MB (4x, =
// 8 XCDs x all of A: the remap gave each XCD a bn-slice x ALL bm, destroying
// the default round-robin's A-sharing; default was already compulsory-only).
// Scans: CB 8->4 (1024 blocks, 4 waves/SIMD vs 2) — scan grids were
// TLP-starved against ~900cy HBM latency; per-channel math order unchanged.

// ---- convert: elementwise f32 -> f16 for x, W_in, W_out (one kernel) ----
__global__ __launch_bounds__(256)
void convert_f16(const float* __restrict__ x,  _Float16* __restrict__ xh,
                 const float* __restrict__ w1, _Float16* __restrict__ w1h,
                 const float* __restrict__ w2, _Float16* __restrict__ w2h) {
    const int n1 = WS_M * WS_D / 8;          // x chunks
    const int n2 = WS_DH * WS_D / 8;         // W_in chunks
    const int n3 = WS_D * WS_DH / 8;         // W_out chunks
    int t = blockIdx.x * 256 + threadIdx.x;
    const float* s; _Float16* d; int off;
    if (t < n1)            { s = x;  d = xh;  off = t; }
    else if (t < n1 + n2)  { s = w1; d = w1h; off = t - n1; }
    else if (t < n1 + n2 + n3) { s = w2; d = w2h; off = t - n1 - n2; }
    else return;
    f32x4 v0 = *(const f32x4*)(s + (size_t)off * 8);
    f32x4 v1 = *(const f32x4*)(s + (size_t)off * 8 + 4);
    f16x8 h;
#pragma unroll
    for (int k = 0; k < 4; ++k) { h[k] = (_Float16)v0[k]; h[4 + k] = (_Float16)v1[k]; }
    *(f16x8*)(d + (size_t)off * 8) = h;
}

// ---- GEMM:  C[m,n] = sum_k A[m,k]*B[n,k] + bias[n] ----
// A [M][K], B [N][K] row-major f16. 128x128 tile, BK=64, dbuf, counted-vmcnt
// ring (2-deep prefetch, vmcnt(8) in-loop, vmcnt(0) only peeled). LDS tile
// [128][64] XOR-swizzled: granule (row,kq) at slot row*8 + (kq^(row&7));
// linear GLDS dest + inverse-swizzled source + swizzled ds_read (rule #21).
// Block mapping: DEFAULT (bm=x, bn=y) — verified compulsory-only HBM fetch.
template<int K, int LDC, int MINB, typename OutT>
__global__ __launch_bounds__(256, MINB)
void gemm_f16(const _Float16* __restrict__ A, const _Float16* __restrict__ B,
              const float* __restrict__ bias, OutT* __restrict__ C)
{
    __shared__ alignas(16) _Float16 sA[2][128 * 64];
    __shared__ alignas(16) _Float16 sB[2][128 * 64];

    const int tid  = threadIdx.x;
    const int lane = tid & 63;
    const int wave = tid >> 6;
    const int wm   = (wave >> 1) * 64;
    const int wn   = (wave & 1) * 64;
    const int m15  = lane & 15;
    const int q    = lane >> 4;

    const int bm = blockIdx.x;
    const int bn = blockIdx.y;

    f32x4 acc[4][4] = {};

    auto stage = [&](int kc0, int buf) {
#pragma unroll
        for (int i = 0; i < 4; ++i) {
            int c   = i * 256 + tid;
            int row = c >> 3;
            int kqs = (c & 7) ^ (row & 7);   // inverse swizzle on SOURCE
            GLDS(A + (size_t)(bm * 128 + row) * K + kc0 + kqs * 8, &sA[buf][c * 8]);
            GLDS(B + (size_t)(bn * 128 + row) * K + kc0 + kqs * 8, &sB[buf][c * 8]);
        }
    };

    auto compute = [&](int bufc) {
#pragma unroll
        for (int kk = 0; kk < 2; ++kk) {
            f16x8 af[4], bf[4];
            int kq = kk * 4 + q;
#pragma unroll
            for (int i = 0; i < 4; ++i) {
                int ra = wm + i * 16 + m15;
                int rb = wn + i * 16 + m15;
                af[i] = *(const f16x8*)&sA[bufc][ra * 64 + ((kq ^ (ra & 7)) << 3)];
                bf[i] = *(const f16x8*)&sB[bufc][rb * 64 + ((kq ^ (rb & 7)) << 3)];
            }
#pragma unroll
            for (int i = 0; i < 4; ++i)
#pragma unroll
                for (int j = 0; j < 4; ++j)
                    acc[i][j] = __builtin_amdgcn_mfma_f32_16x16x32_f16(af[i], bf[j], acc[i][j], 0, 0, 0);
        }
    };

    stage(0, 0);
    stage(64, 1);

    int buf = 0;
    int kc0 = 0;
    for (; kc0 + 64 < K; kc0 += 64, buf ^= 1) {
        asm volatile("s_waitcnt vmcnt(8)" ::: "memory");   // this buf's 8 landed
        __builtin_amdgcn_sched_barrier(0);
        __builtin_amdgcn_s_barrier();

        compute(buf);

        __builtin_amdgcn_sched_barrier(0);
        __builtin_amdgcn_s_barrier();                       // all waves done with buf
        if (kc0 + 128 < K) stage(kc0 + 128, buf);
    }

    asm volatile("s_waitcnt vmcnt(0)" ::: "memory");        // peeled last kstep
    __builtin_amdgcn_sched_barrier(0);
    __builtin_amdgcn_s_barrier();
    compute(buf);

    const int r4 = (lane >> 4) * 4;   // C/D: col=lane&15, row=(lane>>4)*4+reg (m89)
#pragma unroll
    for (int j = 0; j < 4; ++j) {
        int col = bn * 128 + wn + j * 16 + m15;
        float bv = bias[col];
#pragma unroll
        for (int i = 0; i < 4; ++i) {
            int row0 = bm * 128 + wm + i * 16 + r4;
#pragma unroll
            for (int r = 0; r < 4; ++r)
                C[(size_t)(row0 + r) * LDC + col] = (OutT)(acc[i][j][r] + bv);
        }
    }
}

// ---- scan: U[t] = p*U[t-1] + p0*h[t], U[-1]=last;  z[t]=Re(U[t]); y=silu(z) ----
__device__ inline void compute_p(const float* __restrict__ phazor, int c, float& pre, float& pim) {
    float zr = phazor[2 * c], zi = phazor[2 * c + 1];
    float pa = sqrtf(zr * zr + zi * zi);
    float sc = expf(-pa) / pa;       // unit phase * exp(-|p|) magnitude
    pre = zr * sc;
    pim = zi * sc;
}

// phase 1: per-chunk local scan (init 0), write chunk-end states (CB channels)
// Hoisted loads (MLP=16) + CB=4 (1024 blocks = 4 waves/SIMD).
__global__ void scan_local(const _Float16* __restrict__ h, const float* __restrict__ phazor,
                           const float* __restrict__ phazor_init, float* __restrict__ Uend) {
    int idx = blockIdx.x * blockDim.x + threadIdx.x;      // [0, B*NCH*DH/CB)
    int cb   = idx & (CBL - 1);                            // 512 channel-blocks
    int rest = idx >> 9;
    int j    = rest & (NCH - 1);
    int b    = rest >> 7;
    int c0   = cb * CB;
    const int row0 = b * WS_L + j * CHUNK;
    const _Float16* hp = h + (size_t)row0 * WS_DH + c0;
    f16x4 v[CHUNK];
#pragma unroll
    for (int t = 0; t < CHUNK; ++t) v[t] = *(const f16x4*)(hp + (size_t)t * WS_DH);

    float pre[CB], pim[CB], p0r[CB], p0i[CB], ur[CB] = {}, ui[CB] = {};
#pragma unroll
    for (int u = 0; u < CB; ++u) {
        compute_p(phazor, c0 + u, pre[u], pim[u]);
        p0r[u] = phazor_init[2 * (c0 + u)];
        p0i[u] = phazor_init[2 * (c0 + u) + 1];
    }
#pragma unroll
    for (int t = 0; t < CHUNK; ++t) {
#pragma unroll
        for (int u = 0; u < CB; ++u) {
            float hv = (float)v[t][u];
            float nr = fmaf(pre[u], ur[u], fmaf(-pim[u], ui[u], p0r[u] * hv));
            float ni = fmaf(pre[u], ui[u], fmaf( pim[u], ur[u], p0i[u] * hv));
            ur[u] = nr; ui[u] = ni;
        }
    }
    float2* Ue = (float2*)Uend;
    size_t o = ((size_t)(b * NCH + j)) * WS_DH + c0;
#pragma unroll
    for (int u = 0; u < CB; ++u) { float2 w; w.x = ur[u]; w.y = ui[u]; Ue[o + u] = w; }
}

// phase 2: wave-parallel chunk combine (Kogge-Stone over 64 super-chunks of
// coefficient q^2, q = p^CHUNK constant per channel). Unchanged.
__global__ __launch_bounds__(256)
void scan_carry(const float* __restrict__ Uend, float* __restrict__ carry,
                const float* __restrict__ phazor,
                const float* __restrict__ last_re, const float* __restrict__ last_im) {
    __shared__ float2 T[16][NCH + 1];
    const int tid = threadIdx.x;
    const int blk = blockIdx.x;           // [0, B*DH/16) = 512
    const int b   = blk >> 7;             // 128 blocks per batch
    const int c0  = (blk & 127) * 16;

    const float2* Ue = (const float2*)Uend;
    float2* Ca = (float2*)carry;

    // phase A: load Uend[b][k][c0..c0+15] -> T[c_l][k]  (128B segments)
    {
        int c_l = tid & 15, kq = tid >> 4;
#pragma unroll
        for (int pass = 0; pass < NCH / 16; ++pass) {
            int k = pass * 16 + kq;
            T[c_l][k] = Ue[(size_t)(b * NCH + k) * WS_DH + c0 + c_l];
        }
    }
    __syncthreads();

    // phase B: 4 waves x 4 passes = 16 channels; lane j owns chunks 2j, 2j+1
    const int j  = tid & 63;
    const int wv = tid >> 6;
#pragma unroll
    for (int pass = 0; pass < 4; ++pass) {
        int c_l = pass * 4 + wv;
        int c   = c0 + c_l;
        float pre, pim;
        compute_p(phazor, c, pre, pim);
        float qr = pre, qi = pim;          // q = p^CHUNK via 4 squarings (CHUNK=16)
#pragma unroll
        for (int s = 0; s < 4; ++s) { float nr = qr*qr - qi*qi; qi = 2.f*qr*qi; qr = nr; }
        float q2r = qr*qr - qi*qi, q2i = 2.f*qr*qi;   // q^2 = p^32

        float2 L0 = T[c_l][2*j], L1 = T[c_l][2*j + 1];
        // super-chunk local sum: Ls = L1 + q*L0
        float lsr = fmaf(qr, L0.x, fmaf(-qi, L0.y, L1.x));
        float lsi = fmaf(qr, L0.y, fmaf( qi, L0.x, L1.y));
        // w = (q^2)^j via binary expansion of j
        float wr = 1.f, wi = 0.f, sr = q2r, si = q2i;
#pragma unroll
        for (int s = 0; s < 6; ++s) {
            if ((j >> s) & 1) { float nr = wr*sr - wi*si; wi = wr*si + wi*sr; wr = nr; }
            float n2 = sr*sr - si*si; si = 2.f*sr*si; sr = n2;
        }
        // Kogge-Stone inclusive scan: x[j] = sum_i (q^2)^(j-i) * Ls[i]
        float xr = lsr, xi = lsi, ar = q2r, ai = q2i;
#pragma unroll
        for (int o = 1; o < 64; o <<= 1) {
            float rr = __shfl_up(xr, o);
            float ri = __shfl_up(xi, o);
            if (j >= o) {
                xr = fmaf(ar, rr, fmaf(-ai, ri, xr));
                xi = fmaf(ar, ri, fmaf( ai, rr, xi));
            }
            float n2 = ar*ar - ai*ai; ai = 2.f*ar*ai; ar = n2;
        }
        // carry entering super-chunk j: C = w*last + x[j-1]
        float tpr = __shfl_up(xr, 1), tpi = __shfl_up(xi, 1);
        if (j == 0) { tpr = 0.f; tpi = 0.f; }
        float Lre = last_re[b * WS_DH + c], Lim = last_im[b * WS_DH + c];
        float cer = fmaf(wr, Lre, fmaf(-wi, Lim, tpr));
        float cei = fmaf(wr, Lim, fmaf( wi, Lre, tpi));
        // carry[2j] = C ; carry[2j+1] = q*C + L0   (disjoint slots per lane)
        float cor = fmaf(qr, cer, fmaf(-qi, cei, L0.x));
        float coi = fmaf(qr, cei, fmaf( qi, cer, L0.y));
        T[c_l][2*j]     = make_float2(cer, cei);
        T[c_l][2*j + 1] = make_float2(cor, coi);
    }
    __syncthreads();

    // phase C: write carry[b][k][c0..c0+15] back (128B segments)
    {
        int c_l = tid & 15, kq = tid >> 4;
#pragma unroll
        for (int pass = 0; pass < NCH / 16; ++pass) {
            int k = pass * 16 + kq;
            Ca[(size_t)(b * NCH + k) * WS_DH + c0 + c_l] = T[c_l][k];
        }
    }
}

// phase 3: re-scan from carry, silu, write y ROW-MAJOR f16 (hoisted, CB=4).
__global__ void scan_apply(const _Float16* __restrict__ h, const float* __restrict__ phazor,
                           const float* __restrict__ phazor_init, const float* __restrict__ carry,
                           _Float16* __restrict__ yh) {
    int idx = blockIdx.x * blockDim.x + threadIdx.x;
    int cb   = idx & (CBL - 1);
    int rest = idx >> 9;
    int j    = rest & (NCH - 1);
    int b    = rest >> 7;
    int c0   = cb * CB;
    const int row0 = b * WS_L + j * CHUNK;
    const _Float16* hp = h + (size_t)row0 * WS_DH + c0;
    f16x4 v[CHUNK];
#pragma unroll
    for (int t = 0; t < CHUNK; ++t) v[t] = *(const f16x4*)(hp + (size_t)t * WS_DH);

    float pre[CB], pim[CB], p0r[CB], p0i[CB], ur[CB], ui[CB];
    const float2* Ca = (const float2*)carry;
    size_t co = ((size_t)(b * NCH + j)) * WS_DH + c0;
#pragma unroll
    for (int u = 0; u < CB; ++u) {
        compute_p(phazor, c0 + u, pre[u], pim[u]);
        p0r[u] = phazor_init[2 * (c0 + u)];
        p0i[u] = phazor_init[2 * (c0 + u) + 1];
        float2 w = Ca[co + u];
        ur[u] = w.x; ui[u] = w.y;
    }
    _Float16* yp = yh + (size_t)row0 * WS_DH + c0;
#pragma unroll
    for (int t = 0; t < CHUNK; ++t) {
        f16x4 yv;
#pragma unroll
        for (int u = 0; u < CB; ++u) {
            float hv = (float)v[t][u];
            float nr = fmaf(pre[u], ur[u], fmaf(-pim[u], ui[u], p0r[u] * hv));
            float ni = fmaf(pre[u], ui[u], fmaf( pim[u], ur[u], p0i[u] * hv));
            ur[u] = nr; ui[u] = ni;
            float z = nr;                                   // Re(U[t])
            yv[u] = (_Float16)(z / (1.f + expf(-z)));       // silu
        }
        *(f16x4*)(yp + (size_t)t * WS_DH) = yv;
    }
}

extern "C" void kernel_launch(void* const* d_in, const int* in_sizes, int n_in,
                              void* d_out, int out_size, void* d_ws, size_t ws_size,
                              hipStream_t stream)
{
    const float* x       = (const float*)d_in[0];
    const float* W_in    = (const float*)d_in[1];
    const float* b_in    = (const float*)d_in[2];
    const float* W_out   = (const float*)d_in[3];
    const float* b_out   = (const float*)d_in[4];
    const float* phazor  = (const float*)d_in[5];
    const float* ph_init = (const float*)d_in[6];
    const float* last_re = (const float*)d_in[7];
    const float* last_im = (const float*)d_in[8];
    float* out = (float*)d_out;

    // workspace carve-up (76 MB via aliasing).
    char* ws = (char*)d_ws;
    size_t off = 0;
    auto alloc = [&](size_t bytes) {
        char* p = ws + off;
        off += (bytes + 255) & ~(size_t)255;
        return p;
    };
    _Float16* h     = (_Float16*)alloc((size_t)WS_M * WS_DH * 2);    // 32 MB
    _Float16* w2h   = (_Float16*)alloc((size_t)WS_D * WS_DH * 2);    //  4 MB
    char*     alias0 = ws + off;
    _Float16* xh    = (_Float16*)alloc((size_t)WS_M * WS_D * 2);     // 16 MB
    _Float16* w1h   = (_Float16*)alloc((size_t)WS_DH * WS_D * 2);    //  4 MB
    float*    Uend  = (float*)alloc((size_t)WS_B * NCH * WS_DH * 2 * 4); // 8 MB
    alloc((size_t)4 * 1024 * 1024);                                  //  4 MB pad
    float*    carry = (float*)alloc((size_t)WS_B * NCH * WS_DH * 2 * 4); // 8 MB
    _Float16* yh    = (_Float16*)alias0;                             // 32 MB aliased

    // 1) convert all three inputs to f16 row-major (pure elementwise)
    {
        int n = (WS_M * WS_D + WS_DH * WS_D + WS_D * WS_DH) / 8;
        convert_f16<<<dim3((n + 255) / 256), dim3(256), 0, stream>>>(x, xh, W_in, w1h, W_out, w2h);
    }

    // 2) h = x @ W_in^T + b_in   [8192, 2048] f16, grid 64x16 = 1024 blocks
    {
        dim3 g(WS_M / 128, WS_DH / 128);
        gemm_f16<WS_D, WS_DH, 2, _Float16><<<g, dim3(256), 0, stream>>>(xh, w1h, b_in, h);
    }

    // 3) chunked complex scan + silu -> yh (f16 row-major), 3 kernels
    {
        int total = WS_B * NCH * WS_DH / CB;               // 262144 threads, 1024 blocks
        scan_local<<<dim3(total / 256), dim3(256), 0, stream>>>(h, phazor, ph_init, Uend);
        scan_carry<<<dim3(WS_B * WS_DH / 16), dim3(256), 0, stream>>>(Uend, carry, phazor,
                                                                      last_re, last_im);
        scan_apply<<<dim3(total / 256), dim3(256), 0, stream>>>(h, phazor, ph_init, carry, yh);
    }

    // 4) out = yh @ W_out^T + b_out, K=2048, grid 64x8 = 512 blocks
    {
        dim3 g(WS_M / 128, WS_D / 128);
        gemm_f16<WS_DH, WS_D, 2, float><<<g, dim3(256), 0, stream>>>(yh, w2h, b_out, out);
    }
}